// Round 1
// baseline (435.346 us; speedup 1.0000x reference)
//
#include <hip/hip_runtime.h>
#include <hip/hip_bf16.h>

typedef __attribute__((ext_vector_type(8))) short bf16x8;
typedef __attribute__((ext_vector_type(4))) short bf16x4;
typedef __attribute__((ext_vector_type(4))) float f32x4;

#define MFMA16(a, b, c) __builtin_amdgcn_mfma_f32_16x16x32_bf16(a, b, c, 0, 0, 0)

__device__ __forceinline__ unsigned short f2bf(float f) {
  union { float f; unsigned u; } x; x.f = f;
  unsigned r = x.u + 0x7fffu + ((x.u >> 16) & 1u);
  return (unsigned short)(r >> 16);
}

// ---------------- fp32 -> bf16 convert (weights) ----------------
__global__ void cvt_bf16_kernel(const float* __restrict__ src,
                                unsigned short* __restrict__ dst, int n4) {
  int i = blockIdx.x * blockDim.x + threadIdx.x;
  int stride = gridDim.x * blockDim.x;
  for (; i < n4; i += stride) {
    float4 v = reinterpret_cast<const float4*>(src)[i];
    bf16x4 o;
    o[0] = (short)f2bf(v.x); o[1] = (short)f2bf(v.y);
    o[2] = (short)f2bf(v.z); o[3] = (short)f2bf(v.w);
    reinterpret_cast<bf16x4*>(dst)[i] = o;
  }
}

// ---------------- GEMM: out[m,n] = sum_k A[m,k] * Bw[n,k] + bias[n] ----------------
// MODE 0: A fp32, out -> bf16 scattered to [B,H,S,64] (QKV projection)
// MODE 1: A bf16, out -> fp32 row-major [M,N] (final projection)
template <int MODE>
__global__ __launch_bounds__(256) void gemm_kernel(
    const void* __restrict__ Av, const unsigned short* __restrict__ Bw,
    const float* __restrict__ bias, void* __restrict__ outv,
    int M, int N, int K) {
  constexpr int BM = 128, BN = 128, BK = 32, LDT = 40;  // +8 pad: bank-conflict-free
  __shared__ unsigned short As[BM * LDT];
  __shared__ unsigned short Bs[BN * LDT];
  const int tid = threadIdx.x;
  const int lane = tid & 63, wave = tid >> 6;
  const int wr = wave >> 1, wc = wave & 1;
  const int m0 = blockIdx.y * BM, n0 = blockIdx.x * BN;
  const int srow = tid >> 1, sk = (tid & 1) * 16;
  const int rb = lane & 15, kb = (lane >> 4) * 8;
  f32x4 acc[4][4] = {};

  for (int k0 = 0; k0 < K; k0 += BK) {
    // stage A tile (128 x 32)
    if constexpr (MODE == 0) {
      const float* ap = (const float*)Av + (size_t)(m0 + srow) * K + k0 + sk;
      bf16x8 t0, t1;
#pragma unroll
      for (int c = 0; c < 2; ++c) {
        float4 v = *reinterpret_cast<const float4*>(ap + c * 4);
        t0[c * 4 + 0] = (short)f2bf(v.x); t0[c * 4 + 1] = (short)f2bf(v.y);
        t0[c * 4 + 2] = (short)f2bf(v.z); t0[c * 4 + 3] = (short)f2bf(v.w);
      }
#pragma unroll
      for (int c = 0; c < 2; ++c) {
        float4 v = *reinterpret_cast<const float4*>(ap + 8 + c * 4);
        t1[c * 4 + 0] = (short)f2bf(v.x); t1[c * 4 + 1] = (short)f2bf(v.y);
        t1[c * 4 + 2] = (short)f2bf(v.z); t1[c * 4 + 3] = (short)f2bf(v.w);
      }
      *reinterpret_cast<bf16x8*>(&As[srow * LDT + sk]) = t0;
      *reinterpret_cast<bf16x8*>(&As[srow * LDT + sk + 8]) = t1;
    } else {
      const unsigned short* ap = (const unsigned short*)Av + (size_t)(m0 + srow) * K + k0 + sk;
      *reinterpret_cast<bf16x8*>(&As[srow * LDT + sk]) = *reinterpret_cast<const bf16x8*>(ap);
      *reinterpret_cast<bf16x8*>(&As[srow * LDT + sk + 8]) = *reinterpret_cast<const bf16x8*>(ap + 8);
    }
    // stage B tile (128 x 32), Bw is [N,K] row-major (B^T layout)
    {
      const unsigned short* bp = Bw + (size_t)(n0 + srow) * K + k0 + sk;
      *reinterpret_cast<bf16x8*>(&Bs[srow * LDT + sk]) = *reinterpret_cast<const bf16x8*>(bp);
      *reinterpret_cast<bf16x8*>(&Bs[srow * LDT + sk + 8]) = *reinterpret_cast<const bf16x8*>(bp + 8);
    }
    __syncthreads();

    bf16x8 af[4], bf[4];
#pragma unroll
    for (int mi = 0; mi < 4; ++mi)
      af[mi] = *reinterpret_cast<const bf16x8*>(&As[(wr * 64 + mi * 16 + rb) * LDT + kb]);
#pragma unroll
    for (int ni = 0; ni < 4; ++ni)
      bf[ni] = *reinterpret_cast<const bf16x8*>(&Bs[(wc * 64 + ni * 16 + rb) * LDT + kb]);
#pragma unroll
    for (int mi = 0; mi < 4; ++mi)
#pragma unroll
      for (int ni = 0; ni < 4; ++ni)
        acc[mi][ni] = MFMA16(af[mi], bf[ni], acc[mi][ni]);
    __syncthreads();
  }

  // epilogue: C/D layout col=lane&15, row=(lane>>4)*4+j
#pragma unroll
  for (int mi = 0; mi < 4; ++mi) {
#pragma unroll
    for (int ni = 0; ni < 4; ++ni) {
      int col = n0 + wc * 64 + ni * 16 + rb;
      float bv = bias[col];
#pragma unroll
      for (int j = 0; j < 4; ++j) {
        int row = m0 + wr * 64 + mi * 16 + (lane >> 4) * 4 + j;
        float v = acc[mi][ni][j] + bv;
        if constexpr (MODE == 0) {
          int b = row >> 11, s = row & 2047;
          int h = col >> 6, e = col & 63;
          ((unsigned short*)outv)[((size_t)(b * 16 + h) * 2048 + s) * 64 + e] = f2bf(v);
        } else {
          ((float*)outv)[(size_t)row * N + col] = v;
        }
      }
    }
  }
}

// ---------------- flash attention ----------------
// Q,K,V: bf16 [B*H, S, 64]; ctx out: bf16 [B, S, H*64]
__global__ __launch_bounds__(256) void attn_kernel(
    const unsigned short* __restrict__ Qp, const unsigned short* __restrict__ Kp,
    const unsigned short* __restrict__ Vp, unsigned short* __restrict__ ctx) {
  constexpr int S = 2048, H = 16;
  __shared__ unsigned short Ks[64 * 72];
  __shared__ unsigned short Vt[64 * 72];
  __shared__ unsigned short Pl[4 * 16 * 72];
  const int bh = blockIdx.y;  // 0..63
  const int qt = blockIdx.x;  // 0..31
  const int tid = threadIdx.x, wave = tid >> 6, lane = tid & 63;
  const int rb = lane & 15, kb = (lane >> 4) * 8;
  const int qb = qt * 64 + wave * 16;  // this wave's first global q row
  const unsigned short* Qbase = Qp + (size_t)bh * S * 64;
  const unsigned short* Kbase = Kp + (size_t)bh * S * 64;
  const unsigned short* Vbase = Vp + (size_t)bh * S * 64;

  // Q fragments (16 rows x 64 dims): lane holds row rb, k = kc*32 + kb..kb+7
  bf16x8 qf[2];
  qf[0] = *reinterpret_cast<const bf16x8*>(Qbase + (size_t)(qb + rb) * 64 + kb);
  qf[1] = *reinterpret_cast<const bf16x8*>(Qbase + (size_t)(qb + rb) * 64 + 32 + kb);

  float m2[4], lsum[4];
  f32x4 o[4] = {};
#pragma unroll
  for (int j = 0; j < 4; ++j) { m2[j] = -1e30f; lsum[j] = 0.f; }
  const float sc = 0.03125f * 1.4426950408889634f;  // (1/sqrt(1024)) * log2(e)

  const int skey = tid >> 2, sq = tid & 3;  // staging: thread -> (key, 16-col quarter)

  for (int kv0 = 0; kv0 <= qt * 64; kv0 += 64) {
    // ---- stage K (row-major, padded) and V^T ----
    {
      const unsigned short* kp = Kbase + (size_t)(kv0 + skey) * 64 + sq * 16;
      *reinterpret_cast<bf16x8*>(&Ks[skey * 72 + sq * 16]) = *reinterpret_cast<const bf16x8*>(kp);
      *reinterpret_cast<bf16x8*>(&Ks[skey * 72 + sq * 16 + 8]) = *reinterpret_cast<const bf16x8*>(kp + 8);
      const unsigned short* vp = Vbase + (size_t)(kv0 + skey) * 64 + sq * 16;
      bf16x8 v0 = *reinterpret_cast<const bf16x8*>(vp);
      bf16x8 v1 = *reinterpret_cast<const bf16x8*>(vp + 8);
#pragma unroll
      for (int i = 0; i < 8; ++i) Vt[(sq * 16 + i) * 72 + skey] = (unsigned short)v0[i];
#pragma unroll
      for (int i = 0; i < 8; ++i) Vt[(sq * 16 + 8 + i) * 72 + skey] = (unsigned short)v1[i];
    }
    __syncthreads();

    // ---- S = Q K^T (16 q x 64 keys) ----
    f32x4 sacc[4] = {};
#pragma unroll
    for (int n = 0; n < 4; ++n) {
      bf16x8 kf0 = *reinterpret_cast<const bf16x8*>(&Ks[(n * 16 + rb) * 72 + kb]);
      bf16x8 kf1 = *reinterpret_cast<const bf16x8*>(&Ks[(n * 16 + rb) * 72 + 32 + kb]);
      sacc[n] = MFMA16(qf[0], kf0, sacc[n]);
      sacc[n] = MFMA16(qf[1], kf1, sacc[n]);
    }

    // ---- logits (base-2 domain) + causal mask on diagonal tile ----
    const bool diag = (kv0 == qt * 64);
    float lg[4][4];
#pragma unroll
    for (int n = 0; n < 4; ++n) {
      int keyg = kv0 + n * 16 + rb;
#pragma unroll
      for (int j = 0; j < 4; ++j) {
        int qrow = qb + (lane >> 4) * 4 + j;
        float v = sacc[n][j] * sc;
        lg[n][j] = (diag && keyg > qrow) ? -1e30f : v;
      }
    }
    // row max (over 4 n-chunks, then across 16 lanes of the group)
    float mt[4];
#pragma unroll
    for (int j = 0; j < 4; ++j)
      mt[j] = fmaxf(fmaxf(lg[0][j], lg[1][j]), fmaxf(lg[2][j], lg[3][j]));
#pragma unroll
    for (int msk = 1; msk < 16; msk <<= 1)
#pragma unroll
      for (int j = 0; j < 4; ++j) mt[j] = fmaxf(mt[j], __shfl_xor(mt[j], msk, 64));

    float corr[4];
#pragma unroll
    for (int j = 0; j < 4; ++j) {
      float mn = fmaxf(m2[j], mt[j]);
      corr[j] = __builtin_amdgcn_exp2f(m2[j] - mn);
      m2[j] = mn;
    }
    // P = exp2(lg - m2), store to per-wave LDS bounce, accumulate row sums
    float rs[4] = {0.f, 0.f, 0.f, 0.f};
#pragma unroll
    for (int n = 0; n < 4; ++n)
#pragma unroll
      for (int j = 0; j < 4; ++j) {
        float pv = __builtin_amdgcn_exp2f(lg[n][j] - m2[j]);
        rs[j] += pv;
        Pl[(wave * 16 + (lane >> 4) * 4 + j) * 72 + n * 16 + rb] = f2bf(pv);
      }
#pragma unroll
    for (int msk = 1; msk < 16; msk <<= 1)
#pragma unroll
      for (int j = 0; j < 4; ++j) rs[j] += __shfl_xor(rs[j], msk, 64);
#pragma unroll
    for (int j = 0; j < 4; ++j) lsum[j] = lsum[j] * corr[j] + rs[j];
#pragma unroll
    for (int n = 0; n < 4; ++n)
#pragma unroll
      for (int j = 0; j < 4; ++j) o[n][j] *= corr[j];

    // ---- O += P V (P: 16x64 A-frag from wave-local LDS; V^T for B-frag) ----
    bf16x8 pf0 = *reinterpret_cast<const bf16x8*>(&Pl[(wave * 16 + rb) * 72 + kb]);
    bf16x8 pf1 = *reinterpret_cast<const bf16x8*>(&Pl[(wave * 16 + rb) * 72 + 32 + kb]);
#pragma unroll
    for (int n = 0; n < 4; ++n) {
      bf16x8 vf0 = *reinterpret_cast<const bf16x8*>(&Vt[(n * 16 + rb) * 72 + kb]);
      bf16x8 vf1 = *reinterpret_cast<const bf16x8*>(&Vt[(n * 16 + rb) * 72 + 32 + kb]);
      o[n] = MFMA16(pf0, vf0, o[n]);
      o[n] = MFMA16(pf1, vf1, o[n]);
    }
    __syncthreads();
  }

  // epilogue: ctx[b, s, h*64+dim]
  const int b = bh >> 4, h = bh & 15;
#pragma unroll
  for (int n = 0; n < 4; ++n)
#pragma unroll
    for (int j = 0; j < 4; ++j) {
      int srow = qb + (lane >> 4) * 4 + j;
      int dim = n * 16 + rb;
      ctx[((size_t)(b * 2048 + srow) * 1024) + h * 64 + dim] = f2bf(o[n][j] / lsum[j]);
    }
}

extern "C" void kernel_launch(void* const* d_in, const int* in_sizes, int n_in,
                              void* d_out, int out_size, void* d_ws, size_t ws_size,
                              hipStream_t stream) {
  const float* in_q = (const float*)d_in[0];
  const float* in_k = (const float*)d_in[1];
  const float* in_v = (const float*)d_in[2];
  const float* WQw = (const float*)d_in[3];
  const float* WQb = (const float*)d_in[4];
  const float* WKw = (const float*)d_in[5];
  const float* WKb = (const float*)d_in[6];
  const float* WVw = (const float*)d_in[7];
  const float* WVb = (const float*)d_in[8];
  const float* Ww  = (const float*)d_in[9];
  const float* Wb  = (const float*)d_in[10];
  float* out = (float*)d_out;

  constexpr size_t PROJ = (size_t)4 * 16 * 2048 * 64;  // 8,388,608 elems
  constexpr size_t WSZ = (size_t)1024 * 1024;
  unsigned short* wsp = (unsigned short*)d_ws;
  unsigned short* Qp  = wsp;
  unsigned short* Kp  = wsp + PROJ;
  unsigned short* Vp  = wsp + 2 * PROJ;
  unsigned short* ctx = wsp + 3 * PROJ;
  unsigned short* wq16 = wsp + 4 * PROJ;
  unsigned short* wk16 = wq16 + WSZ;
  unsigned short* wv16 = wk16 + WSZ;
  unsigned short* ww16 = wv16 + WSZ;

  // convert weights to bf16
  cvt_bf16_kernel<<<512, 256, 0, stream>>>(WQw, wq16, (int)(WSZ / 4));
  cvt_bf16_kernel<<<512, 256, 0, stream>>>(WKw, wk16, (int)(WSZ / 4));
  cvt_bf16_kernel<<<512, 256, 0, stream>>>(WVw, wv16, (int)(WSZ / 4));
  cvt_bf16_kernel<<<512, 256, 0, stream>>>(Ww, ww16, (int)(WSZ / 4));

  // QKV projections: [8192,1024] x [1024,1024]^T -> [B,H,S,64] bf16
  dim3 gg(8, 64);
  gemm_kernel<0><<<gg, 256, 0, stream>>>(in_q, wq16, WQb, Qp, 8192, 1024, 1024);
  gemm_kernel<0><<<gg, 256, 0, stream>>>(in_k, wk16, WKb, Kp, 8192, 1024, 1024);
  gemm_kernel<0><<<gg, 256, 0, stream>>>(in_v, wv16, WVb, Vp, 8192, 1024, 1024);

  // flash attention -> ctx [B,S,1024] bf16
  attn_kernel<<<dim3(32, 64), 256, 0, stream>>>(Qp, Kp, Vp, ctx);

  // output projection -> fp32 d_out
  gemm_kernel<1><<<gg, 256, 0, stream>>>(ctx, ww16, Wb, out, 8192, 1024, 1024);
}

// Round 2
// 250.175 us; speedup vs baseline: 1.7402x; 1.7402x over previous
//
#include <hip/hip_runtime.h>
#include <hip/hip_bf16.h>

typedef __attribute__((ext_vector_type(8))) short bf16x8;
typedef __attribute__((ext_vector_type(4))) short bf16x4;
typedef __attribute__((ext_vector_type(4))) float f32x4;

#define MFMA16(a, b, c) __builtin_amdgcn_mfma_f32_16x16x32_bf16(a, b, c, 0, 0, 0)

__device__ __forceinline__ unsigned short f2bf(float f) {
  union { float f; unsigned u; } x; x.f = f;
  unsigned r = x.u + 0x7fffu + ((x.u >> 16) & 1u);
  return (unsigned short)(r >> 16);
}

// ---------------- fp32 -> bf16 convert (weights) ----------------
__global__ void cvt_bf16_kernel(const float* __restrict__ src,
                                unsigned short* __restrict__ dst, int n4) {
  int i = blockIdx.x * blockDim.x + threadIdx.x;
  int stride = gridDim.x * blockDim.x;
  for (; i < n4; i += stride) {
    float4 v = reinterpret_cast<const float4*>(src)[i];
    bf16x4 o;
    o[0] = (short)f2bf(v.x); o[1] = (short)f2bf(v.y);
    o[2] = (short)f2bf(v.z); o[3] = (short)f2bf(v.w);
    reinterpret_cast<bf16x4*>(dst)[i] = o;
  }
}

// ---------------- GEMM: out[m,n] = sum_k A[m,k] * B[n,k] + bias ----------------
// MODE 0: A fp32 input, B bf16 weights, bias[col], out bf16 scattered [B,H,S,64]
// MODE 1: A bf16, B bf16 weights, bias[col], out fp32 row-major [M,N]
// MODE 2: A bf16 weights (M=1024), B fp32 input (N=8192), bias[row],
//         out bf16 scattered to V^T layout [BH,64,S] (coalesced stores)
template <int MODE>
__global__ __launch_bounds__(256) void gemm_kernel(
    const void* __restrict__ Av, const void* __restrict__ Bv,
    const float* __restrict__ bias, void* __restrict__ outv,
    int M, int N, int K) {
  constexpr int BM = 128, BN = 128, BK = 32, LDT = 40;
  __shared__ unsigned short As[BM * LDT];
  __shared__ unsigned short Bs[BN * LDT];
  const int tid = threadIdx.x;
  const int lane = tid & 63, wave = tid >> 6;
  const int wr = wave >> 1, wc = wave & 1;
  const int m0 = blockIdx.y * BM, n0 = blockIdx.x * BN;
  const int srow = tid >> 1, sk = (tid & 1) * 16;
  const int rb = lane & 15, kb = (lane >> 4) * 8;
  f32x4 acc[4][4] = {};

  for (int k0 = 0; k0 < K; k0 += BK) {
    // ---- stage A tile ----
    if constexpr (MODE == 0) {
      const float* ap = (const float*)Av + (size_t)(m0 + srow) * K + k0 + sk;
      bf16x8 t0, t1;
#pragma unroll
      for (int c = 0; c < 2; ++c) {
        float4 v = *reinterpret_cast<const float4*>(ap + c * 4);
        t0[c * 4 + 0] = (short)f2bf(v.x); t0[c * 4 + 1] = (short)f2bf(v.y);
        t0[c * 4 + 2] = (short)f2bf(v.z); t0[c * 4 + 3] = (short)f2bf(v.w);
      }
#pragma unroll
      for (int c = 0; c < 2; ++c) {
        float4 v = *reinterpret_cast<const float4*>(ap + 8 + c * 4);
        t1[c * 4 + 0] = (short)f2bf(v.x); t1[c * 4 + 1] = (short)f2bf(v.y);
        t1[c * 4 + 2] = (short)f2bf(v.z); t1[c * 4 + 3] = (short)f2bf(v.w);
      }
      *reinterpret_cast<bf16x8*>(&As[srow * LDT + sk]) = t0;
      *reinterpret_cast<bf16x8*>(&As[srow * LDT + sk + 8]) = t1;
    } else {
      const unsigned short* ap = (const unsigned short*)Av + (size_t)(m0 + srow) * K + k0 + sk;
      *reinterpret_cast<bf16x8*>(&As[srow * LDT + sk]) = *reinterpret_cast<const bf16x8*>(ap);
      *reinterpret_cast<bf16x8*>(&As[srow * LDT + sk + 8]) = *reinterpret_cast<const bf16x8*>(ap + 8);
    }
    // ---- stage B tile ----
    if constexpr (MODE == 2) {
      const float* bp = (const float*)Bv + (size_t)(n0 + srow) * K + k0 + sk;
      bf16x8 t0, t1;
#pragma unroll
      for (int c = 0; c < 2; ++c) {
        float4 v = *reinterpret_cast<const float4*>(bp + c * 4);
        t0[c * 4 + 0] = (short)f2bf(v.x); t0[c * 4 + 1] = (short)f2bf(v.y);
        t0[c * 4 + 2] = (short)f2bf(v.z); t0[c * 4 + 3] = (short)f2bf(v.w);
      }
#pragma unroll
      for (int c = 0; c < 2; ++c) {
        float4 v = *reinterpret_cast<const float4*>(bp + 8 + c * 4);
        t1[c * 4 + 0] = (short)f2bf(v.x); t1[c * 4 + 1] = (short)f2bf(v.y);
        t1[c * 4 + 2] = (short)f2bf(v.z); t1[c * 4 + 3] = (short)f2bf(v.w);
      }
      *reinterpret_cast<bf16x8*>(&Bs[srow * LDT + sk]) = t0;
      *reinterpret_cast<bf16x8*>(&Bs[srow * LDT + sk + 8]) = t1;
    } else {
      const unsigned short* bp = (const unsigned short*)Bv + (size_t)(n0 + srow) * K + k0 + sk;
      *reinterpret_cast<bf16x8*>(&Bs[srow * LDT + sk]) = *reinterpret_cast<const bf16x8*>(bp);
      *reinterpret_cast<bf16x8*>(&Bs[srow * LDT + sk + 8]) = *reinterpret_cast<const bf16x8*>(bp + 8);
    }
    __syncthreads();

    bf16x8 af[4], bfr[4];
#pragma unroll
    for (int mi = 0; mi < 4; ++mi)
      af[mi] = *reinterpret_cast<const bf16x8*>(&As[(wr * 64 + mi * 16 + rb) * LDT + kb]);
#pragma unroll
    for (int ni = 0; ni < 4; ++ni)
      bfr[ni] = *reinterpret_cast<const bf16x8*>(&Bs[(wc * 64 + ni * 16 + rb) * LDT + kb]);
#pragma unroll
    for (int mi = 0; mi < 4; ++mi)
#pragma unroll
      for (int ni = 0; ni < 4; ++ni)
        acc[mi][ni] = MFMA16(af[mi], bfr[ni], acc[mi][ni]);
    __syncthreads();
  }

#pragma unroll
  for (int mi = 0; mi < 4; ++mi) {
#pragma unroll
    for (int ni = 0; ni < 4; ++ni) {
      int col = n0 + wc * 64 + ni * 16 + rb;
      if constexpr (MODE != 2) {
        float bv = bias[col];
#pragma unroll
        for (int j = 0; j < 4; ++j) {
          int row = m0 + wr * 64 + mi * 16 + (lane >> 4) * 4 + j;
          float v = acc[mi][ni][j] + bv;
          if constexpr (MODE == 0) {
            int b = row >> 11, s = row & 2047;
            int h = col >> 6, e = col & 63;
            ((unsigned short*)outv)[((size_t)(b * 16 + h) * 2048 + s) * 64 + e] = f2bf(v);
          } else {
            ((float*)outv)[(size_t)row * N + col] = v;
          }
        }
      } else {
        // MODE 2: row = e-global, col = s-global; out[bh][e][s]
        int bb = col >> 11, s = col & 2047;
#pragma unroll
        for (int j = 0; j < 4; ++j) {
          int row = m0 + wr * 64 + mi * 16 + (lane >> 4) * 4 + j;
          float v = acc[mi][ni][j] + bias[row];
          int h = row >> 6, e = row & 63;
          ((unsigned short*)outv)[((size_t)(bb * 16 + h) * 64 + e) * 2048 + s] = f2bf(v);
        }
      }
    }
  }
}

// ---------------- flash attention (S^T orientation, O^T accumulation) ----------------
// Q,K: bf16 [B*H, S, 64]; Vt: bf16 [B*H, 64, S]; ctx out: bf16 [B, S, H*64]
__global__ __launch_bounds__(256) void attn2_kernel(
    const unsigned short* __restrict__ Qp, const unsigned short* __restrict__ Kp,
    const unsigned short* __restrict__ Vtp, unsigned short* __restrict__ ctx) {
  constexpr int S = 2048;
  __shared__ __align__(16) unsigned short Ks[2][64 * 64];
  __shared__ __align__(16) unsigned short Vs[2][64 * 64];
  __shared__ __align__(16) unsigned short Pl[4][32 * 64];
  const int bx = blockIdx.x;
  const int bh = bx & 63;
  const int qti = 15 - (bx >> 6);  // heavy tiles first
  const int q0 = qti * 128;
  const int tid = threadIdx.x, wave = tid >> 6, lane = tid & 63;
  const int q15 = lane & 15, g = lane >> 4;
  const int qw = q0 + wave * 32;
  const unsigned short* Qb = Qp + (size_t)bh * S * 64;
  const unsigned short* Kb = Kp + (size_t)bh * S * 64;
  const unsigned short* Vb = Vtp + (size_t)bh * 64 * S;

  // Q fragments: lane holds Q[qw+16ni+q15][32kc+8g .. +7]
  bf16x8 qf[2][2];
#pragma unroll
  for (int ni = 0; ni < 2; ++ni)
#pragma unroll
    for (int kc = 0; kc < 2; ++kc)
      qf[ni][kc] = *reinterpret_cast<const bf16x8*>(
          Qb + (size_t)(qw + 16 * ni + q15) * 64 + 32 * kc + 8 * g);

  float m2[2] = {-1e30f, -1e30f}, lsum[2] = {0.f, 0.f};
  f32x4 o[4][2] = {};
  const float sc = 0.03125f * 1.4426950408889634f;  // 1/sqrt(1024) * log2(e)
  const int xsw = (q15 & 7);  // read-side XOR swizzle key (row&7 == q15&7 everywhere)
  const int sswz = ((lane & 7) ^ (lane >> 3)) * 8;  // staging source pre-swizzle
  const int nt = qti * 2 + 2;

  auto stage = [&](int buf, int kv0) {
#pragma unroll
    for (int i = 0; i < 2; ++i) {
      const int ci = (wave * 2 + i) * 64 + lane;     // 16B-chunk index, linear LDS
      const int r = (wave * 2 + i) * 8 + (lane >> 3);  // tile row
      const unsigned short* ksrc = Kb + (size_t)(kv0 + r) * 64 + sswz;
      __builtin_amdgcn_global_load_lds(
          (const __attribute__((address_space(1))) unsigned int*)ksrc,
          (__attribute__((address_space(3))) unsigned int*)&Ks[buf][ci * 8], 16, 0, 0);
      const unsigned short* vsrc = Vb + (size_t)r * S + kv0 + sswz;
      __builtin_amdgcn_global_load_lds(
          (const __attribute__((address_space(1))) unsigned int*)vsrc,
          (__attribute__((address_space(3))) unsigned int*)&Vs[buf][ci * 8], 16, 0, 0);
    }
  };

  stage(0, 0);

  for (int it = 0; it < nt; ++it) {
    __syncthreads();  // staged tile [it] ready (drains vmcnt)
    if (it + 1 < nt) stage((it + 1) & 1, 64 * (it + 1));
    const int kv0 = 64 * it;
    if (kv0 <= qw + 31) {
      const unsigned short* K_ = Ks[it & 1];
      const unsigned short* V_ = Vs[it & 1];
      // ---- S^T = K Q^T: lane holds S^T[16mi+4g+j, q15+16ni] ----
      f32x4 sacc[4][2] = {};
#pragma unroll
      for (int kc = 0; kc < 2; ++kc) {
#pragma unroll
        for (int mi = 0; mi < 4; ++mi) {
          bf16x8 kf = *reinterpret_cast<const bf16x8*>(
              &K_[(16 * mi + q15) * 64 + ((4 * kc + g) ^ xsw) * 8]);
          sacc[mi][0] = MFMA16(kf, qf[0][kc], sacc[mi][0]);
          sacc[mi][1] = MFMA16(kf, qf[1][kc], sacc[mi][1]);
        }
      }
      // ---- scale + causal mask + tile max ----
      const bool diag = (kv0 + 63 > qw);
      float mt[2] = {-1e30f, -1e30f};
#pragma unroll
      for (int mi = 0; mi < 4; ++mi)
#pragma unroll
        for (int ni = 0; ni < 2; ++ni)
#pragma unroll
          for (int j = 0; j < 4; ++j) {
            float v = sacc[mi][ni][j] * sc;
            if (diag && (kv0 + 16 * mi + 4 * g + j > qw + 16 * ni + q15)) v = -1e30f;
            sacc[mi][ni][j] = v;
            mt[ni] = fmaxf(mt[ni], v);
          }
#pragma unroll
      for (int ni = 0; ni < 2; ++ni) {
        mt[ni] = fmaxf(mt[ni], __shfl_xor(mt[ni], 16, 64));
        mt[ni] = fmaxf(mt[ni], __shfl_xor(mt[ni], 32, 64));
      }
      float corr[2], rs[2] = {0.f, 0.f};
#pragma unroll
      for (int ni = 0; ni < 2; ++ni) {
        float mn = fmaxf(m2[ni], mt[ni]);
        corr[ni] = __builtin_amdgcn_exp2f(m2[ni] - mn);
        m2[ni] = mn;
      }
      // ---- P = exp2, pack 4 consecutive keys -> b64 write to Pl ----
#pragma unroll
      for (int mi = 0; mi < 4; ++mi)
#pragma unroll
        for (int ni = 0; ni < 2; ++ni) {
          bf16x4 pk;
#pragma unroll
          for (int j = 0; j < 4; ++j) {
            float p = __builtin_amdgcn_exp2f(sacc[mi][ni][j] - m2[ni]);
            rs[ni] += p;
            pk[j] = (short)f2bf(p);
          }
          *reinterpret_cast<bf16x4*>(
              &Pl[wave][(q15 + 16 * ni) * 64 +
                        ((2 * mi + (g >> 1)) ^ xsw) * 8 + 4 * (g & 1)]) = pk;
        }
#pragma unroll
      for (int ni = 0; ni < 2; ++ni) {
        rs[ni] += __shfl_xor(rs[ni], 16, 64);
        rs[ni] += __shfl_xor(rs[ni], 32, 64);
        lsum[ni] = lsum[ni] * corr[ni] + rs[ni];
      }
#pragma unroll
      for (int mi = 0; mi < 4; ++mi)
#pragma unroll
        for (int ni = 0; ni < 2; ++ni)
#pragma unroll
          for (int j = 0; j < 4; ++j) o[mi][ni][j] *= corr[ni];
      // ---- O^T += V^T P^T : mfma(A=V^T rows, B=P rows) ----
#pragma unroll
      for (int kc = 0; kc < 2; ++kc) {
        bf16x8 pf[2];
#pragma unroll
        for (int ni = 0; ni < 2; ++ni)
          pf[ni] = *reinterpret_cast<const bf16x8*>(
              &Pl[wave][(q15 + 16 * ni) * 64 + ((4 * kc + g) ^ xsw) * 8]);
#pragma unroll
        for (int mi = 0; mi < 4; ++mi) {
          bf16x8 vf = *reinterpret_cast<const bf16x8*>(
              &V_[(16 * mi + q15) * 64 + ((4 * kc + g) ^ xsw) * 8]);
          o[mi][0] = MFMA16(vf, pf[0], o[mi][0]);
          o[mi][1] = MFMA16(vf, pf[1], o[mi][1]);
        }
      }
    }
  }

  // ---- epilogue: lane holds O^T[d=16mi+4g+j, q=q15+16ni]; write ctx[b,q,h*64+d] ----
  const int b = bh >> 4, h = bh & 15;
#pragma unroll
  for (int ni = 0; ni < 2; ++ni) {
    float inv = 1.0f / lsum[ni];
    int q = qw + 16 * ni + q15;
#pragma unroll
    for (int mi = 0; mi < 4; ++mi) {
      bf16x4 pk;
#pragma unroll
      for (int j = 0; j < 4; ++j) pk[j] = (short)f2bf(o[mi][ni][j] * inv);
      *reinterpret_cast<bf16x4*>(
          ctx + ((size_t)(b * 2048 + q) * 1024) + h * 64 + 16 * mi + 4 * g) = pk;
    }
  }
}

extern "C" void kernel_launch(void* const* d_in, const int* in_sizes, int n_in,
                              void* d_out, int out_size, void* d_ws, size_t ws_size,
                              hipStream_t stream) {
  const float* in_q = (const float*)d_in[0];
  const float* in_k = (const float*)d_in[1];
  const float* in_v = (const float*)d_in[2];
  const float* WQw = (const float*)d_in[3];
  const float* WQb = (const float*)d_in[4];
  const float* WKw = (const float*)d_in[5];
  const float* WKb = (const float*)d_in[6];
  const float* WVw = (const float*)d_in[7];
  const float* WVb = (const float*)d_in[8];
  const float* Ww  = (const float*)d_in[9];
  const float* Wb  = (const float*)d_in[10];
  float* out = (float*)d_out;

  constexpr size_t PROJ = (size_t)4 * 16 * 2048 * 64;
  constexpr size_t WSZ = (size_t)1024 * 1024;
  unsigned short* wsp = (unsigned short*)d_ws;
  unsigned short* Qp  = wsp;
  unsigned short* Kp  = wsp + PROJ;
  unsigned short* Vt  = wsp + 2 * PROJ;
  unsigned short* ctx = wsp + 3 * PROJ;
  unsigned short* wq16 = wsp + 4 * PROJ;
  unsigned short* wk16 = wq16 + WSZ;
  unsigned short* wv16 = wk16 + WSZ;
  unsigned short* ww16 = wv16 + WSZ;

  cvt_bf16_kernel<<<512, 256, 0, stream>>>(WQw, wq16, (int)(WSZ / 4));
  cvt_bf16_kernel<<<512, 256, 0, stream>>>(WKw, wk16, (int)(WSZ / 4));
  cvt_bf16_kernel<<<512, 256, 0, stream>>>(WVw, wv16, (int)(WSZ / 4));
  cvt_bf16_kernel<<<512, 256, 0, stream>>>(Ww, ww16, (int)(WSZ / 4));

  // Q,K projections -> [B,H,S,64] bf16
  gemm_kernel<0><<<dim3(8, 64), 256, 0, stream>>>(in_q, wq16, WQb, Qp, 8192, 1024, 1024);
  gemm_kernel<0><<<dim3(8, 64), 256, 0, stream>>>(in_k, wk16, WKb, Kp, 8192, 1024, 1024);
  // V projection computed transposed -> V^T [B*H, 64, S] bf16 (coalesced stores)
  gemm_kernel<2><<<dim3(64, 8), 256, 0, stream>>>(wv16, in_v, WVb, Vt, 1024, 8192, 1024);

  // flash attention -> ctx [B,S,1024] bf16
  attn2_kernel<<<1024, 256, 0, stream>>>(Qp, Kp, Vt, ctx);

  // output projection -> fp32
  gemm_kernel<1><<<dim3(8, 64), 256, 0, stream>>>(ctx, ww16, Wb, out, 8192, 1024, 1024);
}

// Round 3
// 196.545 us; speedup vs baseline: 2.2150x; 1.2729x over previous
//
#include <hip/hip_runtime.h>
#include <hip/hip_bf16.h>

typedef __attribute__((ext_vector_type(8))) short bf16x8;
typedef __attribute__((ext_vector_type(4))) short bf16x4;
typedef __attribute__((ext_vector_type(4))) float f32x4;

#define MFMA16(a, b, c) __builtin_amdgcn_mfma_f32_16x16x32_bf16(a, b, c, 0, 0, 0)

__device__ __forceinline__ unsigned short f2bfn(float f) {
#if defined(__gfx950__)
  __bf16 h = (__bf16)f;
  return __builtin_bit_cast(unsigned short, h);
#else
  union { float f; unsigned u; } x; x.f = f;
  unsigned r = x.u + 0x7fffu + ((x.u >> 16) & 1u);
  return (unsigned short)(r >> 16);
#endif
}

// ---------------- fp32 -> bf16 conversion ----------------
__device__ __forceinline__ void cvt_body(const float* __restrict__ s,
                                         unsigned short* __restrict__ d, int n8) {
  int i = blockIdx.x * blockDim.x + threadIdx.x;
  int st = gridDim.x * blockDim.x;
  for (; i < n8; i += st) {
    const float4* sp = reinterpret_cast<const float4*>(s) + 2 * (size_t)i;
    float4 a = sp[0], b = sp[1];
    bf16x8 o;
    o[0] = (short)f2bfn(a.x); o[1] = (short)f2bfn(a.y);
    o[2] = (short)f2bfn(a.z); o[3] = (short)f2bfn(a.w);
    o[4] = (short)f2bfn(b.x); o[5] = (short)f2bfn(b.y);
    o[6] = (short)f2bfn(b.z); o[7] = (short)f2bfn(b.w);
    reinterpret_cast<bf16x8*>(d)[i] = o;
  }
}

__global__ void cvt1_kernel(const float* __restrict__ s, unsigned short* __restrict__ d, int n8) {
  cvt_body(s, d, n8);
}

__global__ void cvt_w_kernel(const float* s0, const float* s1, const float* s2, const float* s3,
                             unsigned short* d0, unsigned short* d1, unsigned short* d2,
                             unsigned short* d3, int n8) {
  const float* s; unsigned short* d;
  switch (blockIdx.y) {
    case 0: s = s0; d = d0; break;
    case 1: s = s1; d = d1; break;
    case 2: s = s2; d = d2; break;
    default: s = s3; d = d3; break;
  }
  cvt_body(s, d, n8);
}

// ---------------- GEMM: out[m,n] = sum_k A[m,k]*B[n,k] + bias ----------------
// All operands bf16 [rows, K] row-major. global_load_lds staging, XOR-swizzled
// LDS, double-buffered, 1 barrier/iter.
// MODE 0: bias[col], out bf16 scattered [B,H,S,64] (row=b*2048+s, col=h*64+e)
// MODE 1: bias[col], out fp32 row-major [M,N]
// MODE 2: bias[row], out bf16 V^T layout [BH,64,S] (row=e-global, col=s-global)
template <int MODE>
__global__ __launch_bounds__(256) void gemm_kernel(
    const unsigned short* __restrict__ Av, const unsigned short* __restrict__ Bv,
    const float* __restrict__ bias, void* __restrict__ outv,
    int M, int N, int K) {
  constexpr int BM = 128, BN = 128, BK = 64;
  __shared__ __align__(16) unsigned short As[2][BM * BK];
  __shared__ __align__(16) unsigned short Bs[2][BN * BK];
  const int tid = threadIdx.x;
  const int lane = tid & 63, wave = tid >> 6;
  const int wr = wave >> 1, wc = wave & 1;
  const int m0 = blockIdx.y * BM, n0 = blockIdx.x * BN;
  const int rb = lane & 15, g = lane >> 4;
  const int swz = ((lane & 7) ^ ((lane >> 3) & 7)) * 8;  // pre-swizzled source offset
  f32x4 acc[4][4] = {};

  const unsigned short* Ab = Av + (size_t)m0 * K;
  const unsigned short* Bb = Bv + (size_t)n0 * K;

  auto stage = [&](int buf, int k0) {
#pragma unroll
    for (int i = 0; i < 4; ++i) {
      const int c = wave * 256 + i * 64 + lane;  // 16B-chunk index (linear LDS)
      const int r = c >> 3;                      // tile row
      __builtin_amdgcn_global_load_lds(
          (const __attribute__((address_space(1))) unsigned int*)(Ab + (size_t)r * K + k0 + swz),
          (__attribute__((address_space(3))) unsigned int*)&As[buf][c * 8], 16, 0, 0);
      __builtin_amdgcn_global_load_lds(
          (const __attribute__((address_space(1))) unsigned int*)(Bb + (size_t)r * K + k0 + swz),
          (__attribute__((address_space(3))) unsigned int*)&Bs[buf][c * 8], 16, 0, 0);
    }
  };

  const int nt = K / BK;
  stage(0, 0);
  int cur = 0;
  for (int t = 0; t < nt; ++t) {
    __syncthreads();  // staged tile [t] ready (vmcnt+lgkm drained at barrier)
    if (t + 1 < nt) stage(cur ^ 1, (t + 1) * BK);
    const unsigned short* A_ = As[cur];
    const unsigned short* B_ = Bs[cur];
#pragma unroll
    for (int kc = 0; kc < 2; ++kc) {
      bf16x8 af[4], bfr[4];
#pragma unroll
      for (int mi = 0; mi < 4; ++mi)
        af[mi] = *reinterpret_cast<const bf16x8*>(
            &A_[(wr * 64 + mi * 16 + rb) * 64 + (((kc * 4 + g) ^ (rb & 7)) * 8)]);
#pragma unroll
      for (int ni = 0; ni < 4; ++ni)
        bfr[ni] = *reinterpret_cast<const bf16x8*>(
            &B_[(wc * 64 + ni * 16 + rb) * 64 + (((kc * 4 + g) ^ (rb & 7)) * 8)]);
#pragma unroll
      for (int mi = 0; mi < 4; ++mi)
#pragma unroll
        for (int ni = 0; ni < 4; ++ni)
          acc[mi][ni] = MFMA16(af[mi], bfr[ni], acc[mi][ni]);
    }
    cur ^= 1;
  }

#pragma unroll
  for (int mi = 0; mi < 4; ++mi) {
#pragma unroll
    for (int ni = 0; ni < 4; ++ni) {
      int col = n0 + wc * 64 + ni * 16 + rb;
      if constexpr (MODE != 2) {
        float bv = bias[col];
#pragma unroll
        for (int j = 0; j < 4; ++j) {
          int row = m0 + wr * 64 + mi * 16 + g * 4 + j;
          float v = acc[mi][ni][j] + bv;
          if constexpr (MODE == 0) {
            int b = row >> 11, s = row & 2047;
            int h = col >> 6, e = col & 63;
            ((unsigned short*)outv)[((size_t)(b * 16 + h) * 2048 + s) * 64 + e] = f2bfn(v);
          } else {
            ((float*)outv)[(size_t)row * N + col] = v;
          }
        }
      } else {
        int bb = col >> 11, s = col & 2047;
#pragma unroll
        for (int j = 0; j < 4; ++j) {
          int row = m0 + wr * 64 + mi * 16 + g * 4 + j;
          float v = acc[mi][ni][j] + bias[row];
          int h = row >> 6, e = row & 63;
          ((unsigned short*)outv)[((size_t)(bb * 16 + h) * 64 + e) * 2048 + s] = f2bfn(v);
        }
      }
    }
  }
}

// ---------------- flash attention (S^T orientation, O^T accumulation) ----------------
// Q,K: bf16 [B*H, S, 64]; Vt: bf16 [B*H, 64, S]; ctx out: bf16 [B, S, H*64]
__global__ __launch_bounds__(256) void attn2_kernel(
    const unsigned short* __restrict__ Qp, const unsigned short* __restrict__ Kp,
    const unsigned short* __restrict__ Vtp, unsigned short* __restrict__ ctx) {
  constexpr int S = 2048;
  __shared__ __align__(16) unsigned short Ks[2][64 * 64];
  __shared__ __align__(16) unsigned short Vs[2][64 * 64];
  __shared__ __align__(16) unsigned short Pl[4][32 * 64];
  const int bx = blockIdx.x;
  const int bh = bx & 63;
  const int qti = 15 - (bx >> 6);  // heavy tiles first
  const int q0 = qti * 128;
  const int tid = threadIdx.x, wave = tid >> 6, lane = tid & 63;
  const int q15 = lane & 15, g = lane >> 4;
  const int qw = q0 + wave * 32;
  const unsigned short* Qb = Qp + (size_t)bh * S * 64;
  const unsigned short* Kb = Kp + (size_t)bh * S * 64;
  const unsigned short* Vb = Vtp + (size_t)bh * 64 * S;

  bf16x8 qf[2][2];
#pragma unroll
  for (int ni = 0; ni < 2; ++ni)
#pragma unroll
    for (int kc = 0; kc < 2; ++kc)
      qf[ni][kc] = *reinterpret_cast<const bf16x8*>(
          Qb + (size_t)(qw + 16 * ni + q15) * 64 + 32 * kc + 8 * g);

  float m2[2] = {-1e30f, -1e30f}, nm2[2] = {0.f, 0.f}, lsum[2] = {0.f, 0.f};
  f32x4 o[4][2] = {};
  const float sc = 0.03125f * 1.4426950408889634f;  // 1/sqrt(1024) * log2(e)
  const float TH = 8.0f / sc;                       // defer-max threshold (raw units)
  const int xsw = (q15 & 7);
  const int sswz = ((lane & 7) ^ (lane >> 3)) * 8;
  const int nt = qti * 2 + 2;

  auto stage = [&](int buf, int kv0) {
#pragma unroll
    for (int i = 0; i < 2; ++i) {
      const int ci = (wave * 2 + i) * 64 + lane;
      const int r = (wave * 2 + i) * 8 + (lane >> 3);
      const unsigned short* ksrc = Kb + (size_t)(kv0 + r) * 64 + sswz;
      __builtin_amdgcn_global_load_lds(
          (const __attribute__((address_space(1))) unsigned int*)ksrc,
          (__attribute__((address_space(3))) unsigned int*)&Ks[buf][ci * 8], 16, 0, 0);
      const unsigned short* vsrc = Vb + (size_t)r * S + kv0 + sswz;
      __builtin_amdgcn_global_load_lds(
          (const __attribute__((address_space(1))) unsigned int*)vsrc,
          (__attribute__((address_space(3))) unsigned int*)&Vs[buf][ci * 8], 16, 0, 0);
    }
  };

  stage(0, 0);

  for (int it = 0; it < nt; ++it) {
    __syncthreads();
    if (it + 1 < nt) stage((it + 1) & 1, 64 * (it + 1));
    const int kv0 = 64 * it;
    if (kv0 <= qw + 31) {
      const unsigned short* K_ = Ks[it & 1];
      const unsigned short* V_ = Vs[it & 1];
      // ---- S^T = K Q^T (raw logits) ----
      f32x4 sacc[4][2] = {};
      __builtin_amdgcn_s_setprio(1);
#pragma unroll
      for (int kc = 0; kc < 2; ++kc) {
#pragma unroll
        for (int mi = 0; mi < 4; ++mi) {
          bf16x8 kf = *reinterpret_cast<const bf16x8*>(
              &K_[(16 * mi + q15) * 64 + ((4 * kc + g) ^ xsw) * 8]);
          sacc[mi][0] = MFMA16(kf, qf[0][kc], sacc[mi][0]);
          sacc[mi][1] = MFMA16(kf, qf[1][kc], sacc[mi][1]);
        }
      }
      __builtin_amdgcn_s_setprio(0);
      // ---- causal mask (diagonal tiles only; wave-uniform branch) ----
      if (kv0 + 63 > qw) {
#pragma unroll
        for (int mi = 0; mi < 4; ++mi)
#pragma unroll
          for (int ni = 0; ni < 2; ++ni)
#pragma unroll
            for (int j = 0; j < 4; ++j)
              if (kv0 + 16 * mi + 4 * g + j > qw + 16 * ni + q15) sacc[mi][ni][j] = -1e30f;
      }
      // ---- tile max (raw domain) ----
      float mt[2] = {-1e30f, -1e30f};
#pragma unroll
      for (int mi = 0; mi < 4; ++mi)
#pragma unroll
        for (int ni = 0; ni < 2; ++ni)
#pragma unroll
          for (int j = 0; j < 4; ++j) mt[ni] = fmaxf(mt[ni], sacc[mi][ni][j]);
#pragma unroll
      for (int ni = 0; ni < 2; ++ni) {
        mt[ni] = fmaxf(mt[ni], __shfl_xor(mt[ni], 16, 64));
        mt[ni] = fmaxf(mt[ni], __shfl_xor(mt[ni], 32, 64));
      }
      // ---- defer-max: only rescale when max grew by > TH ----
      bool need = (mt[0] > m2[0] + TH) || (mt[1] > m2[1] + TH);
      if (__any((int)need)) {
#pragma unroll
        for (int ni = 0; ni < 2; ++ni) {
          float mn = fmaxf(m2[ni], mt[ni]);
          float corr = __builtin_amdgcn_exp2f((m2[ni] - mn) * sc);
          m2[ni] = mn;
          nm2[ni] = -mn * sc;
          lsum[ni] *= corr;
#pragma unroll
          for (int mi = 0; mi < 4; ++mi)
#pragma unroll
            for (int j = 0; j < 4; ++j) o[mi][ni][j] *= corr;
        }
      }
      // ---- P = exp2(fma(raw, sc, -sc*m2)) -> bf16 -> LDS bounce ----
      float rs[2] = {0.f, 0.f};
#pragma unroll
      for (int mi = 0; mi < 4; ++mi)
#pragma unroll
        for (int ni = 0; ni < 2; ++ni) {
          bf16x4 pk;
#pragma unroll
          for (int j = 0; j < 4; ++j) {
            float p = __builtin_amdgcn_exp2f(fmaf(sacc[mi][ni][j], sc, nm2[ni]));
            rs[ni] += p;
            pk[j] = (short)f2bfn(p);
          }
          *reinterpret_cast<bf16x4*>(
              &Pl[wave][(q15 + 16 * ni) * 64 +
                        ((2 * mi + (g >> 1)) ^ xsw) * 8 + 4 * (g & 1)]) = pk;
        }
#pragma unroll
      for (int ni = 0; ni < 2; ++ni) {
        rs[ni] += __shfl_xor(rs[ni], 16, 64);
        rs[ni] += __shfl_xor(rs[ni], 32, 64);
        lsum[ni] += rs[ni];
      }
      // ---- O^T += V^T P^T ----
      __builtin_amdgcn_s_setprio(1);
#pragma unroll
      for (int kc = 0; kc < 2; ++kc) {
        bf16x8 pf[2];
#pragma unroll
        for (int ni = 0; ni < 2; ++ni)
          pf[ni] = *reinterpret_cast<const bf16x8*>(
              &Pl[wave][(q15 + 16 * ni) * 64 + ((4 * kc + g) ^ xsw) * 8]);
#pragma unroll
        for (int mi = 0; mi < 4; ++mi) {
          bf16x8 vf = *reinterpret_cast<const bf16x8*>(
              &V_[(16 * mi + q15) * 64 + ((4 * kc + g) ^ xsw) * 8]);
          o[mi][0] = MFMA16(vf, pf[0], o[mi][0]);
          o[mi][1] = MFMA16(vf, pf[1], o[mi][1]);
        }
      }
      __builtin_amdgcn_s_setprio(0);
    }
  }

  const int b = bh >> 4, h = bh & 15;
#pragma unroll
  for (int ni = 0; ni < 2; ++ni) {
    float inv = 1.0f / lsum[ni];
    int q = qw + 16 * ni + q15;
#pragma unroll
    for (int mi = 0; mi < 4; ++mi) {
      bf16x4 pk;
#pragma unroll
      for (int j = 0; j < 4; ++j) pk[j] = (short)f2bfn(o[mi][ni][j] * inv);
      *reinterpret_cast<bf16x4*>(
          ctx + ((size_t)(b * 2048 + q) * 1024) + h * 64 + 16 * mi + 4 * g) = pk;
    }
  }
}

extern "C" void kernel_launch(void* const* d_in, const int* in_sizes, int n_in,
                              void* d_out, int out_size, void* d_ws, size_t ws_size,
                              hipStream_t stream) {
  const float* in_q = (const float*)d_in[0];
  const float* in_k = (const float*)d_in[1];
  const float* in_v = (const float*)d_in[2];
  const float* WQw = (const float*)d_in[3];
  const float* WQb = (const float*)d_in[4];
  const float* WKw = (const float*)d_in[5];
  const float* WKb = (const float*)d_in[6];
  const float* WVw = (const float*)d_in[7];
  const float* WVb = (const float*)d_in[8];
  const float* Ww  = (const float*)d_in[9];
  const float* Wb  = (const float*)d_in[10];
  float* out = (float*)d_out;

  constexpr size_t PROJ = (size_t)4 * 16 * 2048 * 64;  // 8,388,608 elems
  constexpr size_t WSZ = (size_t)1024 * 1024;
  unsigned short* wsp = (unsigned short*)d_ws;
  unsigned short* Qp   = wsp;
  unsigned short* Kp   = wsp + PROJ;
  unsigned short* Vt   = wsp + 2 * PROJ;
  unsigned short* in16 = wsp + 3 * PROJ;  // reused q->k->v, then aliased as ctx
  unsigned short* ctx  = in16;
  unsigned short* wq16 = wsp + 4 * PROJ;
  unsigned short* wk16 = wq16 + WSZ;
  unsigned short* wv16 = wk16 + WSZ;
  unsigned short* ww16 = wv16 + WSZ;

  // weights -> bf16 (batched)
  cvt_w_kernel<<<dim3(256, 4), 256, 0, stream>>>(WQw, WKw, WVw, Ww,
                                                 wq16, wk16, wv16, ww16, (int)(WSZ / 8));
  // Q projection
  cvt1_kernel<<<2048, 256, 0, stream>>>(in_q, in16, (int)(PROJ / 8));
  gemm_kernel<0><<<dim3(8, 64), 256, 0, stream>>>(in16, wq16, WQb, Qp, 8192, 1024, 1024);
  // K projection
  cvt1_kernel<<<2048, 256, 0, stream>>>(in_k, in16, (int)(PROJ / 8));
  gemm_kernel<0><<<dim3(8, 64), 256, 0, stream>>>(in16, wk16, WKb, Kp, 8192, 1024, 1024);
  // V projection, computed transposed -> V^T [B*H, 64, S]
  cvt1_kernel<<<2048, 256, 0, stream>>>(in_v, in16, (int)(PROJ / 8));
  gemm_kernel<2><<<dim3(64, 8), 256, 0, stream>>>(wv16, in16, WVb, Vt, 1024, 8192, 1024);

  // flash attention -> ctx [B,S,1024] bf16 (aliases in16; V-GEMM already consumed it)
  attn2_kernel<<<1024, 256, 0, stream>>>(Qp, Kp, Vt, ctx);

  // output projection -> fp32
  gemm_kernel<1><<<dim3(8, 64), 256, 0, stream>>>(ctx, ww16, Wb, out, 8192, 1024, 1024);
}

// Round 5
// 192.480 us; speedup vs baseline: 2.2618x; 1.0211x over previous
//
#include <hip/hip_runtime.h>
#include <hip/hip_bf16.h>

typedef __attribute__((ext_vector_type(8))) short bf16x8;
typedef __attribute__((ext_vector_type(4))) short bf16x4;
typedef __attribute__((ext_vector_type(4))) float f32x4;
typedef __attribute__((ext_vector_type(16))) float f32x16;

#define MFMA16(a, b, c) __builtin_amdgcn_mfma_f32_16x16x32_bf16(a, b, c, 0, 0, 0)
#define MFMA32(a, b, c) __builtin_amdgcn_mfma_f32_32x32x16_bf16(a, b, c, 0, 0, 0)

__device__ __forceinline__ unsigned short f2bfn(float f) {
#if defined(__gfx950__)
  __bf16 h = (__bf16)f;
  return __builtin_bit_cast(unsigned short, h);
#else
  union { float f; unsigned u; } x; x.f = f;
  unsigned r = x.u + 0x7fffu + ((x.u >> 16) & 1u);
  return (unsigned short)(r >> 16);
#endif
}

// swap a's upper 32 lanes with b's lower 32 lanes (compiler-managed permlane)
__device__ __forceinline__ void plswap(unsigned& a, unsigned& b) {
  auto r = __builtin_amdgcn_permlane32_swap(a, b, false, false);
  a = r[0];
  b = r[1];
}

__device__ __forceinline__ unsigned cvtpk(float lo, float hi) {
  unsigned w;
  asm("v_cvt_pk_bf16_f32 %0, %1, %2" : "=v"(w) : "v"(lo), "v"(hi));
  return w;
}

// ---------------- fp32 -> bf16 conversion ----------------
__device__ __forceinline__ void cvt_body(const float* __restrict__ s,
                                         unsigned short* __restrict__ d, int n8) {
  int i = blockIdx.x * blockDim.x + threadIdx.x;
  int st = gridDim.x * blockDim.x;
  for (; i < n8; i += st) {
    const float4* sp = reinterpret_cast<const float4*>(s) + 2 * (size_t)i;
    float4 a = sp[0], b = sp[1];
    bf16x8 o;
    o[0] = (short)f2bfn(a.x); o[1] = (short)f2bfn(a.y);
    o[2] = (short)f2bfn(a.z); o[3] = (short)f2bfn(a.w);
    o[4] = (short)f2bfn(b.x); o[5] = (short)f2bfn(b.y);
    o[6] = (short)f2bfn(b.z); o[7] = (short)f2bfn(b.w);
    reinterpret_cast<bf16x8*>(d)[i] = o;
  }
}

__global__ void cvt1_kernel(const float* __restrict__ s, unsigned short* __restrict__ d, int n8) {
  cvt_body(s, d, n8);
}

__global__ void cvt_w_kernel(const float* s0, const float* s1, const float* s2, const float* s3,
                             unsigned short* d0, unsigned short* d1, unsigned short* d2,
                             unsigned short* d3, int n8) {
  const float* s; unsigned short* d;
  switch (blockIdx.y) {
    case 0: s = s0; d = d0; break;
    case 1: s = s1; d = d1; break;
    case 2: s = s2; d = d2; break;
    default: s = s3; d = d3; break;
  }
  cvt_body(s, d, n8);
}

// ---------------- GEMM: out[m,n] = sum_k A[m,k]*B[n,k] + bias ----------------
// All operands bf16 [rows, K] row-major. global_load_lds staging, XOR-swizzled
// LDS, double-buffered, 1 barrier/iter.
// MODE 0: bias[col], out bf16 scattered [B,H,S,64]
// MODE 1: bias[col], out fp32 row-major [M,N]
// MODE 2: bias[row], out bf16 V^T layout [BH,64,S]
template <int MODE>
__global__ __launch_bounds__(256) void gemm_kernel(
    const unsigned short* __restrict__ Av, const unsigned short* __restrict__ Bv,
    const float* __restrict__ bias, void* __restrict__ outv,
    int M, int N, int K) {
  constexpr int BM = 128, BN = 128, BK = 64;
  __shared__ __align__(16) unsigned short As[2][BM * BK];
  __shared__ __align__(16) unsigned short Bs[2][BN * BK];
  const int tid = threadIdx.x;
  const int lane = tid & 63, wave = tid >> 6;
  const int wr = wave >> 1, wc = wave & 1;
  const int m0 = blockIdx.y * BM, n0 = blockIdx.x * BN;
  const int rb = lane & 15, g = lane >> 4;
  const int swz = ((lane & 7) ^ ((lane >> 3) & 7)) * 8;
  f32x4 acc[4][4] = {};

  const unsigned short* Ab = Av + (size_t)m0 * K;
  const unsigned short* Bb = Bv + (size_t)n0 * K;

  auto stage = [&](int buf, int k0) {
#pragma unroll
    for (int i = 0; i < 4; ++i) {
      const int c = wave * 256 + i * 64 + lane;
      const int r = c >> 3;
      __builtin_amdgcn_global_load_lds(
          (const __attribute__((address_space(1))) unsigned int*)(Ab + (size_t)r * K + k0 + swz),
          (__attribute__((address_space(3))) unsigned int*)&As[buf][c * 8], 16, 0, 0);
      __builtin_amdgcn_global_load_lds(
          (const __attribute__((address_space(1))) unsigned int*)(Bb + (size_t)r * K + k0 + swz),
          (__attribute__((address_space(3))) unsigned int*)&Bs[buf][c * 8], 16, 0, 0);
    }
  };

  const int nt = K / BK;
  stage(0, 0);
  int cur = 0;
  for (int t = 0; t < nt; ++t) {
    __syncthreads();
    if (t + 1 < nt) stage(cur ^ 1, (t + 1) * BK);
    const unsigned short* A_ = As[cur];
    const unsigned short* B_ = Bs[cur];
#pragma unroll
    for (int kc = 0; kc < 2; ++kc) {
      bf16x8 af[4], bfr[4];
#pragma unroll
      for (int mi = 0; mi < 4; ++mi)
        af[mi] = *reinterpret_cast<const bf16x8*>(
            &A_[(wr * 64 + mi * 16 + rb) * 64 + (((kc * 4 + g) ^ (rb & 7)) * 8)]);
#pragma unroll
      for (int ni = 0; ni < 4; ++ni)
        bfr[ni] = *reinterpret_cast<const bf16x8*>(
            &B_[(wc * 64 + ni * 16 + rb) * 64 + (((kc * 4 + g) ^ (rb & 7)) * 8)]);
#pragma unroll
      for (int mi = 0; mi < 4; ++mi)
#pragma unroll
        for (int ni = 0; ni < 4; ++ni)
          acc[mi][ni] = MFMA16(af[mi], bfr[ni], acc[mi][ni]);
    }
    cur ^= 1;
  }

#pragma unroll
  for (int mi = 0; mi < 4; ++mi) {
#pragma unroll
    for (int ni = 0; ni < 4; ++ni) {
      int col = n0 + wc * 64 + ni * 16 + rb;
      if constexpr (MODE != 2) {
        float bv = bias[col];
#pragma unroll
        for (int j = 0; j < 4; ++j) {
          int row = m0 + wr * 64 + mi * 16 + g * 4 + j;
          float v = acc[mi][ni][j] + bv;
          if constexpr (MODE == 0) {
            int b = row >> 11, s = row & 2047;
            int h = col >> 6, e = col & 63;
            ((unsigned short*)outv)[((size_t)(b * 16 + h) * 2048 + s) * 64 + e] = f2bfn(v);
          } else {
            ((float*)outv)[(size_t)row * N + col] = v;
          }
        }
      } else {
        int bb = col >> 11, s = col & 2047;
#pragma unroll
        for (int j = 0; j < 4; ++j) {
          int row = m0 + wr * 64 + mi * 16 + g * 4 + j;
          float v = acc[mi][ni][j] + bias[row];
          int h = row >> 6, e = row & 63;
          ((unsigned short*)outv)[((size_t)(bb * 16 + h) * 64 + e) * 2048 + s] = f2bfn(v);
        }
      }
    }
  }
}

// ---------------- flash attention: 32x32 swapped, in-register softmax ----------------
// Q,K: bf16 [B*H, S, 64]; Vt: bf16 [B*H, 64, S]; ctx out: bf16 [B, S, H*64]
// Per wave: 32 q-cols (lane&31 owns one q); S^T = mfma(K, Q^T); softmax in regs;
// PV B-frag assembled via cvt_pk + permlane32_swap (no LDS P-bounce).
__global__ __launch_bounds__(256) void attn3_kernel(
    const unsigned short* __restrict__ Qp, const unsigned short* __restrict__ Kp,
    const unsigned short* __restrict__ Vtp, unsigned short* __restrict__ ctx) {
  constexpr int S = 2048;
  __shared__ __align__(16) unsigned short Ks[2][64 * 64];
  __shared__ __align__(16) unsigned short Vs[2][64 * 64];
  const int bx = blockIdx.x;
  const int bh = bx & 63;
  const int qti = 15 - (bx >> 6);  // heavy tiles first
  const int q0 = qti * 128;
  const int tid = threadIdx.x, wave = tid >> 6, lane = tid & 63;
  const int l31 = lane & 31, hb = lane >> 5, hb4 = hb * 4;
  const int x7 = l31 & 7;  // read-side XOR swizzle key
  const int qw = q0 + wave * 32;
  const unsigned short* Qb = Qp + (size_t)bh * S * 64;
  const unsigned short* Kb = Kp + (size_t)bh * S * 64;
  const unsigned short* Vb = Vtp + (size_t)bh * 64 * S;

  // Q B-fragments: lane holds Q[qw+l31][16kc+8hb .. +7]
  bf16x8 qg[4];
#pragma unroll
  for (int kc = 0; kc < 4; ++kc)
    qg[kc] = *reinterpret_cast<const bf16x8*>(
        Qb + (size_t)(qw + l31) * 64 + 16 * kc + 8 * hb);

  float m2 = -1e30f, nm2 = 0.f, lsum = 0.f;
  f32x16 o[2] = {};
  const float sc = 0.03125f * 1.4426950408889634f;  // 1/sqrt(1024) * log2(e)
  const float TH = 8.0f / sc;                       // defer-max threshold (raw)
  const int sswz = ((lane & 7) ^ (lane >> 3)) * 8;  // staging source pre-swizzle
  const int nt = qti * 2 + 2;

  auto stage = [&](int buf, int kv0) {
#pragma unroll
    for (int i = 0; i < 2; ++i) {
      const int ci = (wave * 2 + i) * 64 + lane;       // 16B chunk (linear LDS)
      const int r = (wave * 2 + i) * 8 + (lane >> 3);  // tile row
      __builtin_amdgcn_global_load_lds(
          (const __attribute__((address_space(1))) unsigned int*)(Kb + (size_t)(kv0 + r) * 64 + sswz),
          (__attribute__((address_space(3))) unsigned int*)&Ks[buf][ci * 8], 16, 0, 0);
      __builtin_amdgcn_global_load_lds(
          (const __attribute__((address_space(1))) unsigned int*)(Vb + (size_t)r * S + kv0 + sswz),
          (__attribute__((address_space(3))) unsigned int*)&Vs[buf][ci * 8], 16, 0, 0);
    }
  };

  stage(0, 0);

  for (int it = 0; it < nt; ++it) {
    __syncthreads();  // staged tile [it] ready
    if (it + 1 < nt) stage((it + 1) & 1, 64 * (it + 1));
    const int kv0 = 64 * it;
    if (kv0 <= qw + 31) {
      const unsigned short* K_ = Ks[it & 1];
      const unsigned short* V_ = Vs[it & 1];
      // ---- S^T = K Q^T: lane owns q-col = qw + l31; k rows in regs ----
      f32x16 sacc[2] = {};
      __builtin_amdgcn_s_setprio(1);
#pragma unroll
      for (int kc = 0; kc < 4; ++kc) {
        bf16x8 kf0 = *reinterpret_cast<const bf16x8*>(
            &K_[l31 * 64 + ((2 * kc + hb) ^ x7) * 8]);
        bf16x8 kf1 = *reinterpret_cast<const bf16x8*>(
            &K_[(32 + l31) * 64 + ((2 * kc + hb) ^ x7) * 8]);
        sacc[0] = MFMA32(kf0, qg[kc], sacc[0]);
        sacc[1] = MFMA32(kf1, qg[kc], sacc[1]);
      }
      __builtin_amdgcn_s_setprio(0);
      // ---- causal mask (diag tiles only): k = kv0+32mi+(r&3)+8(r>>2)+hb4 ----
      if (kv0 + 63 > qw) {
        const int qrel = qw + l31 - kv0;
#pragma unroll
        for (int mi = 0; mi < 2; ++mi)
#pragma unroll
          for (int r = 0; r < 16; ++r) {
            int koff = 32 * mi + (r & 3) + 8 * (r >> 2) + hb4;
            if (koff > qrel) sacc[mi][r] = -1e30f;
          }
      }
      // ---- tile max: in-reg + cross-half combine ----
      float mt = -1e30f;
#pragma unroll
      for (int mi = 0; mi < 2; ++mi)
#pragma unroll
        for (int r = 0; r < 16; ++r) mt = fmaxf(mt, sacc[mi][r]);
      mt = fmaxf(mt, __shfl_xor(mt, 32, 64));
      // ---- defer-max rescale ----
      if (__any((int)(mt > m2 + TH))) {
        float mn = fmaxf(m2, mt);
        float corr = __builtin_amdgcn_exp2f((m2 - mn) * sc);
        m2 = mn; nm2 = -mn * sc;
        lsum *= corr;
#pragma unroll
        for (int db = 0; db < 2; ++db)
#pragma unroll
          for (int r = 0; r < 16; ++r) o[db][r] *= corr;
      }
      // ---- P = exp2(fma(s,sc,nm2)); pack to bf16 pairs in regs ----
      float rs = 0.f;
      unsigned pw[2][8];
#pragma unroll
      for (int mi = 0; mi < 2; ++mi) {
        float p[16];
#pragma unroll
        for (int r = 0; r < 16; ++r) {
          p[r] = __builtin_amdgcn_exp2f(fmaf(sacc[mi][r], sc, nm2));
          rs += p[r];
        }
#pragma unroll
        for (int i = 0; i < 8; ++i) pw[mi][i] = cvtpk(p[2 * i], p[2 * i + 1]);
      }
      lsum += rs;  // per-lane half-sum; combined across lane^32 at epilogue
      // ---- assemble PV B-frags: lane needs k = 16c + 8hb + 0..7 ----
#pragma unroll
      for (int mi = 0; mi < 2; ++mi) {
        plswap(pw[mi][0], pw[mi][2]);
        plswap(pw[mi][1], pw[mi][3]);
        plswap(pw[mi][4], pw[mi][6]);
        plswap(pw[mi][5], pw[mi][7]);
      }
      // ---- O^T += V^T P^T ----
      __builtin_amdgcn_s_setprio(1);
#pragma unroll
      for (int c = 0; c < 4; ++c) {
        union { unsigned u[4]; bf16x8 v; } pu;
        pu.u[0] = pw[c >> 1][(c & 1) * 4 + 0];
        pu.u[1] = pw[c >> 1][(c & 1) * 4 + 1];
        pu.u[2] = pw[c >> 1][(c & 1) * 4 + 2];
        pu.u[3] = pw[c >> 1][(c & 1) * 4 + 3];
#pragma unroll
        for (int db = 0; db < 2; ++db) {
          bf16x8 vf = *reinterpret_cast<const bf16x8*>(
              &V_[(32 * db + l31) * 64 + ((2 * c + hb) ^ x7) * 8]);
          o[db] = MFMA32(vf, pu.v, o[db]);
        }
      }
      __builtin_amdgcn_s_setprio(0);
    }
  }

  // ---- epilogue: lane holds O^T[d = 32db+(r&3)+8(r>>2)+hb4][q = qw+l31] ----
  const float tot = lsum + __shfl_xor(lsum, 32, 64);
  const float inv = 1.0f / tot;
  const int b = bh >> 4, h = bh & 15;
  const int q = qw + l31;
  unsigned short* cp = ctx + ((size_t)(b * 2048 + q) * 1024) + h * 64;
#pragma unroll
  for (int db = 0; db < 2; ++db)
#pragma unroll
    for (int i = 0; i < 8; ++i) {
      unsigned w = cvtpk(o[db][2 * i] * inv, o[db][2 * i + 1] * inv);
      int d = 32 * db + ((2 * i) & 3) + 8 * (i >> 1) + hb4;
      *reinterpret_cast<unsigned*>(cp + d) = w;
    }
}

extern "C" void kernel_launch(void* const* d_in, const int* in_sizes, int n_in,
                              void* d_out, int out_size, void* d_ws, size_t ws_size,
                              hipStream_t stream) {
  const float* in_q = (const float*)d_in[0];
  const float* in_k = (const float*)d_in[1];
  const float* in_v = (const float*)d_in[2];
  const float* WQw = (const float*)d_in[3];
  const float* WQb = (const float*)d_in[4];
  const float* WKw = (const float*)d_in[5];
  const float* WKb = (const float*)d_in[6];
  const float* WVw = (const float*)d_in[7];
  const float* WVb = (const float*)d_in[8];
  const float* Ww  = (const float*)d_in[9];
  const float* Wb  = (const float*)d_in[10];
  float* out = (float*)d_out;

  constexpr size_t PROJ = (size_t)4 * 16 * 2048 * 64;  // 8,388,608 elems
  constexpr size_t WSZ = (size_t)1024 * 1024;
  unsigned short* wsp = (unsigned short*)d_ws;
  unsigned short* Qp   = wsp;
  unsigned short* Kp   = wsp + PROJ;
  unsigned short* Vt   = wsp + 2 * PROJ;
  unsigned short* in16 = wsp + 3 * PROJ;  // reused q->k->v, then aliased as ctx
  unsigned short* ctx  = in16;
  unsigned short* wq16 = wsp + 4 * PROJ;
  unsigned short* wk16 = wq16 + WSZ;
  unsigned short* wv16 = wk16 + WSZ;
  unsigned short* ww16 = wv16 + WSZ;

  // weights -> bf16 (batched)
  cvt_w_kernel<<<dim3(256, 4), 256, 0, stream>>>(WQw, WKw, WVw, Ww,
                                                 wq16, wk16, wv16, ww16, (int)(WSZ / 8));
  // Q projection
  cvt1_kernel<<<2048, 256, 0, stream>>>(in_q, in16, (int)(PROJ / 8));
  gemm_kernel<0><<<dim3(8, 64), 256, 0, stream>>>(in16, wq16, WQb, Qp, 8192, 1024, 1024);
  // K projection
  cvt1_kernel<<<2048, 256, 0, stream>>>(in_k, in16, (int)(PROJ / 8));
  gemm_kernel<0><<<dim3(8, 64), 256, 0, stream>>>(in16, wk16, WKb, Kp, 8192, 1024, 1024);
  // V projection, computed transposed -> V^T [B*H, 64, S]
  cvt1_kernel<<<2048, 256, 0, stream>>>(in_v, in16, (int)(PROJ / 8));
  gemm_kernel<2><<<dim3(64, 8), 256, 0, stream>>>(wv16, in16, WVb, Vt, 1024, 8192, 1024);

  // flash attention -> ctx [B,S,1024] bf16 (aliases in16; V-GEMM already consumed it)
  attn3_kernel<<<1024, 256, 0, stream>>>(Qp, Kp, Vt, ctx);

  // output projection -> fp32
  gemm_kernel<1><<<dim3(8, 64), 256, 0, stream>>>(ctx, ww16, Wb, out, 8192, 1024, 1024);
}